// Round 12
// baseline (105.202 us; speedup 1.0000x reference)
//
#include <hip/hip_runtime.h>
#include <hip/hip_bf16.h>
#include <math.h>

// PolicyHead, staged-byte-minimized, BM=128 + super-period A staging:
//   kLN = LayerNorm(key_table); bqk = kLN.bq
//   Wk  = Wq @ kLN^T (4096x128-pad f16) FRAGMENT-TILED (Bf)
//   part[ks] = A[:, ks*1024:+1024] @ Wk-slice  (split-K x4)
//   out = log_softmax(mask(gather(sum part + bqk)/16) + bias)
//
// Model (R8/R11): staged-byte rate ~13 B/cyc/CU. B-staging total scales as
// (NUM_B/BM)*1MB -> BM=128 halves it to 0.5MB/CU (A 1.05 -> 1.55 total).
// BK=32 compute, but A staged in 2-iter SUPER-PERIODS at 256B/row contiguity
// (BK=32's 128B rows would regress HBM granularity, cf R5). LDS = A 2x32KB
// + B 2x8KB = 80KB exactly -> 2 blocks/CU. Per wave per iter: 1 B + 2 A
// gl_lds (B issued FIRST); waits vmcnt(3) even / vmcnt(5) odd / 1,0 tail.
//
// ws: [0,1MB) Bf f16 | [1MB,+83K) tableLN | [1MB+128K,+512B) bqk
//     [2MB,+33.5MB) part f32 [4][16384][128]

typedef _Float16 half8_t __attribute__((ext_vector_type(8)));
typedef float    f32x4_t __attribute__((ext_vector_type(4)));

#define NUM_B 16384
#define D_IN  4096
#define D_Q   256
#define N_ACT 40

__device__ __forceinline__ half8_t cvt8(const float4 a, const float4 b) {
  half8_t h;
  h[0] = (_Float16)a.x; h[1] = (_Float16)a.y; h[2] = (_Float16)a.z; h[3] = (_Float16)a.w;
  h[4] = (_Float16)b.x; h[5] = (_Float16)b.y; h[6] = (_Float16)b.z; h[7] = (_Float16)b.w;
  return h;
}
__device__ __forceinline__ void gl_lds16f(const float* g, float* l) {
  __builtin_amdgcn_global_load_lds(
      (const __attribute__((address_space(1))) void*)g,
      (__attribute__((address_space(3))) void*)l, 16, 0, 0);
}
__device__ __forceinline__ void gl_lds16h(const _Float16* g, _Float16* l) {
  __builtin_amdgcn_global_load_lds(
      (const __attribute__((address_space(1))) void*)g,
      (__attribute__((address_space(3))) void*)l, 16, 0, 0);
}

// ---------------------------------------------------------------------------
__global__ __launch_bounds__(256) void ln_table_k(const float* __restrict__ kt,
                                                  const float* __restrict__ gamma,
                                                  const float* __restrict__ beta,
                                                  const float* __restrict__ bq,
                                                  float* __restrict__ out,
                                                  float* __restrict__ bqk) {
  __shared__ float red[8];
  __shared__ float red2[4];
  const int t = threadIdx.x, r = blockIdx.x;
  float v = kt[r * 256 + t];
  float s = v, sq = v * v;
#pragma unroll
  for (int off = 1; off < 64; off <<= 1) {
    s  += __shfl_xor(s, off);
    sq += __shfl_xor(sq, off);
  }
  if ((t & 63) == 0) { red[t >> 6] = s; red[4 + (t >> 6)] = sq; }
  __syncthreads();
  s  = red[0] + red[1] + red[2] + red[3];
  sq = red[4] + red[5] + red[6] + red[7];
  const float mu  = s * (1.0f / 256.0f);
  const float var = sq * (1.0f / 256.0f) - mu * mu;
  const float inv = 1.0f / sqrtf(var + 1e-5f);
  const float o = (v - mu) * inv * gamma[t] + beta[t];
  out[r * 256 + t] = o;
  float p = o * bq[t];
#pragma unroll
  for (int off = 1; off < 64; off <<= 1) p += __shfl_xor(p, off);
  if ((t & 63) == 0) red2[t >> 6] = p;
  __syncthreads();
  if (t == 0) bqk[r] = red2[0] + red2[1] + red2[2] + red2[3];
}

// ---------------------------------------------------------------------------
// Wk = Wq(4096x256) @ kLN^T(256x81->128 zero-pad), f16, fragment-tiled:
// element (k,n) -> halves idx ((k>>5)*8+(n>>4))*512 + (((k>>3)&3)*16+(n&15))*8 + (k&7)
__global__ __launch_bounds__(256) void wk_gemm_k(const float* __restrict__ Wq,
                                                 const float* __restrict__ tbl,
                                                 _Float16* __restrict__ Bf) {
  const int lane = threadIdx.x & 63, w = threadIdx.x >> 6;
  const int wm = w >> 1, wn = w & 1;
  const int m0 = blockIdx.x * 64 + wm * 32;
  const int n0 = wn * 64;
  const int fr = lane & 15, fg = lane >> 4;
  f32x4_t acc[2][4] = {};
  for (int k0 = 0; k0 < 256; k0 += 32) {
    half8_t af[2], bf[4];
#pragma unroll
    for (int i = 0; i < 2; ++i) {
      const float* p = Wq + (size_t)(m0 + i * 16 + fr) * D_Q + k0 + fg * 8;
      af[i] = cvt8(*(const float4*)p, *(const float4*)(p + 4));
    }
#pragma unroll
    for (int j = 0; j < 4; ++j) {
      const int n = n0 + j * 16 + fr;
      if (n < 81) {
        const float* p = tbl + (size_t)n * D_Q + k0 + fg * 8;
        bf[j] = cvt8(*(const float4*)p, *(const float4*)(p + 4));
      } else {
        bf[j] = (half8_t)(_Float16)0.0f;
      }
    }
#pragma unroll
    for (int i = 0; i < 2; ++i)
#pragma unroll
      for (int j = 0; j < 4; ++j)
        acc[i][j] = __builtin_amdgcn_mfma_f32_16x16x32_f16(af[i], bf[j], acc[i][j], 0, 0, 0);
  }
#pragma unroll
  for (int i = 0; i < 2; ++i)
#pragma unroll
    for (int j = 0; j < 4; ++j)
#pragma unroll
      for (int r = 0; r < 4; ++r) {
        const int k = m0 + i * 16 + fg * 4 + r;
        const int n = n0 + j * 16 + fr;
        const int kt32 = k >> 5, fgb = (k >> 3) & 3, e = k & 7;
        const int jg = n >> 4, frb = n & 15;
        Bf[(((size_t)kt32 * 8 + jg) * 64 + fgb * 16 + frb) * 8 + e] =
            (_Float16)acc[i][j][r];
      }
}

// ---------------------------------------------------------------------------
// GEMM partials: block (bx, ks) owns 128 batch rows x 128 cols x K-slice
// ks*1024..+1024 (32 iters of BK=32; A staged per 2-iter super, 256B/row).
// 512 thr / 8 waves, wave tile 32 rows x 64 cols (wm=w>>1, wn=w&1).
// LDS: Af[2][8192] f32 (super-slots, src-XOR u^(r&7) on 16 units/row),
//      Bl[2][4096] f16 (per-kt slots, linear Bf chunk). 80KB total.
__global__ __launch_bounds__(512) void gemm_part_k(const float* __restrict__ A,
                                                   const _Float16* __restrict__ Bf,
                                                   float* __restrict__ part) {
  __shared__ __align__(16) char smem[81920];
  float*    Afs = (float*)smem;                 // [2][8192] f32  (64KB)
  _Float16* Bls = (_Float16*)(smem + 65536);    // [2][4096] f16  (16KB)

  const int t = threadIdx.x, lane = t & 63, w = t >> 6;
  const int fr = lane & 15, fg = lane >> 4;
  const int ks = blockIdx.y;
  const size_t row0 = (size_t)blockIdx.x * 128;
  const int k0 = ks * 1024;

  // B stage (1 instr/wave): tile TB -> slot TB&1
#define STAGE_B(TB)                                                           \
  do {                                                                        \
    gl_lds16h(Bf + ((size_t)(ks * 32 + (TB))) * 4096 + w * 512 + lane * 8,    \
              Bls + ((TB)&1) * 4096 + w * 512);                               \
  } while (0)
  // A half-stage (2 instr/wave): super SU (64 floats/row), half HF (64 rows)
  // instr id = HF*16 + w*2 + q : rows id*4 + (lane>>4), unit u=lane&15,
  // source unit u^(r&7), LDS linear at slot(SU&1)*8192 + id*256.
#define STAGE_A(SU, HF)                                                       \
  do {                                                                        \
    float* abase = Afs + ((SU)&1) * 8192;                                     \
    _Pragma("unroll") for (int q_ = 0; q_ < 2; ++q_) {                        \
      const int id_ = (HF)*16 + w * 2 + q_;                                   \
      const int r_ = id_ * 4 + (lane >> 4);                                   \
      gl_lds16f(A + (size_t)(row0 + r_) * D_IN + k0 + (SU)*64 +               \
                    (((lane & 15) ^ (r_ & 7)) << 2),                          \
                abase + id_ * 256);                                           \
    }                                                                         \
  } while (0)

  // frag read offsets: af for row R=wm*32+i*16+fr, kt-parity kh, unit pair
  // g=kh*8+fg*2+h -> LDS float idx R*64 + (g^(R&7))*4 (+ slot*8192)
  int aoff[2][2][2];  // [i][kh][h]
#pragma unroll
  for (int i = 0; i < 2; ++i)
#pragma unroll
    for (int kh = 0; kh < 2; ++kh)
#pragma unroll
      for (int h = 0; h < 2; ++h) {
        const int R = (w >> 1) * 32 + i * 16 + fr;
        aoff[i][kh][h] = R * 64 + (((kh * 8 + fg * 2 + h) ^ (R & 7)) << 2);
      }
  const int wm = w >> 1, wn = w & 1;
  int boff[4];
#pragma unroll
  for (int j = 0; j < 4; ++j) boff[j] = (wn * 4 + j) * 512 + lane * 8;

  f32x4_t acc[2][4] = {};

  // prologue: B(0) then A super 0 (both halves)
  STAGE_B(0);
  STAGE_A(0, 0);
  STAGE_A(0, 1);

  for (int kt = 0; kt < 32; ++kt) {
    // issue next-stage loads: B first (FIFO: wait-for-B frees A windows)
    if (kt < 31) STAGE_B(kt + 1);
    if (kt < 30) {
      if ((kt & 1) == 0) STAGE_A((kt >> 1) + 1, 0);
      else               STAGE_A((kt >> 1) + 1, 1);
    }
    __builtin_amdgcn_sched_barrier(0);
    if (kt < 30) {
      if ((kt & 1) == 0) asm volatile("s_waitcnt vmcnt(3)" ::: "memory");
      else               asm volatile("s_waitcnt vmcnt(5)" ::: "memory");
    } else if (kt == 30) {
      asm volatile("s_waitcnt vmcnt(1)" ::: "memory");
    } else {
      asm volatile("s_waitcnt vmcnt(0)" ::: "memory");
    }
    __builtin_amdgcn_s_barrier();
    __builtin_amdgcn_sched_barrier(0);

    const float*    Ap = Afs + ((kt >> 1) & 1) * 8192;
    const _Float16* Bp = Bls + (kt & 1) * 4096;
    const int kh = kt & 1;
    half8_t bfv[4];
#pragma unroll
    for (int j = 0; j < 4; ++j) bfv[j] = *(const half8_t*)(Bp + boff[j]);
#pragma unroll
    for (int i = 0; i < 2; ++i) {
      const float4 x0 = *(const float4*)(Ap + aoff[i][kh][0]);
      const float4 x1 = *(const float4*)(Ap + aoff[i][kh][1]);
      const half8_t af = cvt8(x0, x1);
#pragma unroll
      for (int j = 0; j < 4; ++j)
        acc[i][j] = __builtin_amdgcn_mfma_f32_16x16x32_f16(af, bfv[j], acc[i][j], 0, 0, 0);
    }
    asm volatile("s_waitcnt lgkmcnt(0)" ::: "memory");
    __builtin_amdgcn_s_barrier();
    __builtin_amdgcn_sched_barrier(0);
  }
#undef STAGE_A
#undef STAGE_B

  // epilogue: C/D layout row=fg*4+r, col=j*16+fr  [m89]
  float* pb = part + ((size_t)ks * NUM_B + row0) * 128;
#pragma unroll
  for (int i = 0; i < 2; ++i)
#pragma unroll
    for (int j = 0; j < 4; ++j) {
      const int col = wn * 64 + j * 16 + fr;
#pragma unroll
      for (int r = 0; r < 4; ++r)
        pb[(size_t)(wm * 32 + i * 16 + fg * 4 + r) * 128 + col] = acc[i][j][r];
    }
}

// ---------------------------------------------------------------------------
// Coalesced split-K reduce + gather + bias + log_softmax. One wave per row.
// Lane l holds cols {2l,2l+1}; gather via shuffle from lane aidx>>1.
__global__ __launch_bounds__(256) void softmax_k(const float* __restrict__ part,
                                                 const float* __restrict__ bqk,
                                                 const int* __restrict__ va,
                                                 const int* __restrict__ phase,
                                                 const int* __restrict__ trick,
                                                 const float* __restrict__ psig,
                                                 float* __restrict__ out) {
  const int t = threadIdx.x;
  const int lane = t & 63, w = t >> 6;
  const int b = blockIdx.x * 4 + w;

  float sx = 0.f, sy = 0.f;
#pragma unroll
  for (int ks = 0; ks < 4; ++ks) {
    const float2 v = *(const float2*)&part[((size_t)ks * NUM_B + b) * 128 + lane * 2];
    sx += v.x; sy += v.y;
  }

  int rank = -1, suit = 0;
  if (lane < N_ACT) {
    rank = va[((size_t)b * N_ACT + lane) * 2];
    suit = va[((size_t)b * N_ACT + lane) * 2 + 1];
  }
  const int ph = phase[b];
  const bool valid = (rank >= 0);
  const int aidx = valid ? (suit == 4 ? 80 : ph * 40 + suit * 9 + rank) : -1;
  const int nvalid = __popcll(__ballot(valid));

  const int srcl = valid ? (aidx >> 1) : 0;
  const float v0 = __shfl(sx, srcl);
  const float v1 = __shfl(sy, srcl);

  float attn_l = -INFINITY;
  if (valid) attn_l = (((aidx & 1) ? v1 : v0) + bqk[aidx]) * 0.0625f;  // /sqrt(256)

  if (ph == 1 && lane == 0) {
    const float ps = psig[trick[b]];
    const float nv = (float)nvalid;
    const float wv = (nv == 1.0f) ? 0.0f
                                  : logf(fmaxf((1.0f - ps) / ps * (nv - 1.0f), 1e-5f));
    attn_l += wv;
  }

  float m = attn_l;
#pragma unroll
  for (int off = 1; off < 64; off <<= 1) m = fmaxf(m, __shfl_xor(m, off));
  const float e = expf(attn_l - m);
  float ssum = e;
#pragma unroll
  for (int off = 1; off < 64; off <<= 1) ssum += __shfl_xor(ssum, off);
  const float o = attn_l - m - logf(ssum);
  // finite sentinel at masked positions (ref has -inf; (-inf)-(-inf)=NaN fails)
  if (lane < N_ACT) out[(size_t)b * N_ACT + lane] = valid ? o : -3.0e38f;
}

// ---------------------------------------------------------------------------
extern "C" void kernel_launch(void* const* d_in, const int* in_sizes, int n_in,
                              void* d_out, int out_size, void* d_ws, size_t ws_size,
                              hipStream_t stream) {
  const float* backbone = (const float*)d_in[0];
  const int*   va       = (const int*)d_in[1];
  const int*   phase    = (const int*)d_in[2];
  const int*   trick    = (const int*)d_in[3];
  const float* Wq       = (const float*)d_in[4];
  const float* bq       = (const float*)d_in[5];
  const float* keytab   = (const float*)d_in[6];
  const float* gamma    = (const float*)d_in[7];
  const float* beta     = (const float*)d_in[8];
  const float* psig     = (const float*)d_in[9];
  float* out = (float*)d_out;

  char* ws = (char*)d_ws;
  _Float16* Bf   = (_Float16*)ws;                             // 1 MB
  float* tableLN = (float*)(ws + (1u << 20));                 // 83 KB
  float* bqk     = (float*)(ws + (1u << 20) + (128u << 10));  // 324 B
  float* part    = (float*)(ws + (2u << 20));                 // 33.5 MB

  ln_table_k<<<dim3(81), 256, 0, stream>>>(keytab, gamma, beta, bq, tableLN, bqk);
  wk_gemm_k<<<dim3(64), 256, 0, stream>>>(Wq, tableLN, Bf);
  gemm_part_k<<<dim3(NUM_B / 128, 4), 512, 0, stream>>>(backbone, Bf, part);
  softmax_k<<<dim3(NUM_B / 4), 256, 0, stream>>>(part, bqk, va, phase, trick,
                                                 psig, out);
}

// Round 13
// 103.593 us; speedup vs baseline: 1.0155x; 1.0155x over previous
//
#include <hip/hip_runtime.h>
#include <hip/hip_bf16.h>
#include <math.h>

// PolicyHead, m97-shaped GEMM (single-buffer, 2-barrier, high block TLP):
//   kLN = LayerNorm(key_table); bqk = kLN.bq
//   Wk  = Wq @ kLN^T (4096x128-pad f16) FRAGMENT-TILED (Bf)
//   part[ks] = A[:, ks*1024:+1024] @ Wk-slice  (split-K x4)
//   out = log_softmax(mask(gather(sum part + bqk)/16) + bias)
//
// Cross-round rate data: gl_lds staging hit 13.5 B/cyc/CU at 3 blocks/CU
// (R8), 11.4 at 2 (R11); learn_hip m97 hits ~21 with a PLAIN __syncthreads
// single-buffer loop, ~3 blocks/CU, 16 MFMA/wave/period. Emulate: 256thr/4
// waves, BM=64 BN=128 BK=64, wave tile 32x64 (16 MFMA/wave/iter), LDS 32KB
// single-buffered (A 16KB f32 swz + B 16KB linear), split-K x4 -> grid
// (256,4)=1024 blocks = 4/CU co-resident (launch_bounds(256,4)). Staged
// bytes same as R11 (2.05MB/CU); the bet is on RATE via TLP + period shape.
//
// ws: [0,1MB) Bf f16 | [1MB,+83K) tableLN | [1MB+128K,+512B) bqk
//     [2MB,+33.5MB) part f32 [4][16384][128]

typedef _Float16 half8_t __attribute__((ext_vector_type(8)));
typedef float    f32x4_t __attribute__((ext_vector_type(4)));

#define NUM_B 16384
#define D_IN  4096
#define D_Q   256
#define N_ACT 40

__device__ __forceinline__ half8_t cvt8(const float4 a, const float4 b) {
  half8_t h;
  h[0] = (_Float16)a.x; h[1] = (_Float16)a.y; h[2] = (_Float16)a.z; h[3] = (_Float16)a.w;
  h[4] = (_Float16)b.x; h[5] = (_Float16)b.y; h[6] = (_Float16)b.z; h[7] = (_Float16)b.w;
  return h;
}
__device__ __forceinline__ void gl_lds16f(const float* g, float* l) {
  __builtin_amdgcn_global_load_lds(
      (const __attribute__((address_space(1))) void*)g,
      (__attribute__((address_space(3))) void*)l, 16, 0, 0);
}
__device__ __forceinline__ void gl_lds16h(const _Float16* g, _Float16* l) {
  __builtin_amdgcn_global_load_lds(
      (const __attribute__((address_space(1))) void*)g,
      (__attribute__((address_space(3))) void*)l, 16, 0, 0);
}

// ---------------------------------------------------------------------------
__global__ __launch_bounds__(256) void ln_table_k(const float* __restrict__ kt,
                                                  const float* __restrict__ gamma,
                                                  const float* __restrict__ beta,
                                                  const float* __restrict__ bq,
                                                  float* __restrict__ out,
                                                  float* __restrict__ bqk) {
  __shared__ float red[8];
  __shared__ float red2[4];
  const int t = threadIdx.x, r = blockIdx.x;
  float v = kt[r * 256 + t];
  float s = v, sq = v * v;
#pragma unroll
  for (int off = 1; off < 64; off <<= 1) {
    s  += __shfl_xor(s, off);
    sq += __shfl_xor(sq, off);
  }
  if ((t & 63) == 0) { red[t >> 6] = s; red[4 + (t >> 6)] = sq; }
  __syncthreads();
  s  = red[0] + red[1] + red[2] + red[3];
  sq = red[4] + red[5] + red[6] + red[7];
  const float mu  = s * (1.0f / 256.0f);
  const float var = sq * (1.0f / 256.0f) - mu * mu;
  const float inv = 1.0f / sqrtf(var + 1e-5f);
  const float o = (v - mu) * inv * gamma[t] + beta[t];
  out[r * 256 + t] = o;
  float p = o * bq[t];
#pragma unroll
  for (int off = 1; off < 64; off <<= 1) p += __shfl_xor(p, off);
  if ((t & 63) == 0) red2[t >> 6] = p;
  __syncthreads();
  if (t == 0) bqk[r] = red2[0] + red2[1] + red2[2] + red2[3];
}

// ---------------------------------------------------------------------------
// Wk = Wq(4096x256) @ kLN^T(256x81->128 zero-pad), f16, fragment-tiled:
// element (k,n) -> halves idx ((k>>5)*8+(n>>4))*512 + (((k>>3)&3)*16+(n&15))*8 + (k&7)
__global__ __launch_bounds__(256) void wk_gemm_k(const float* __restrict__ Wq,
                                                 const float* __restrict__ tbl,
                                                 _Float16* __restrict__ Bf) {
  const int lane = threadIdx.x & 63, w = threadIdx.x >> 6;
  const int wm = w >> 1, wn = w & 1;
  const int m0 = blockIdx.x * 64 + wm * 32;
  const int n0 = wn * 64;
  const int fr = lane & 15, fg = lane >> 4;
  f32x4_t acc[2][4] = {};
  for (int k0 = 0; k0 < 256; k0 += 32) {
    half8_t af[2], bf[4];
#pragma unroll
    for (int i = 0; i < 2; ++i) {
      const float* p = Wq + (size_t)(m0 + i * 16 + fr) * D_Q + k0 + fg * 8;
      af[i] = cvt8(*(const float4*)p, *(const float4*)(p + 4));
    }
#pragma unroll
    for (int j = 0; j < 4; ++j) {
      const int n = n0 + j * 16 + fr;
      if (n < 81) {
        const float* p = tbl + (size_t)n * D_Q + k0 + fg * 8;
        bf[j] = cvt8(*(const float4*)p, *(const float4*)(p + 4));
      } else {
        bf[j] = (half8_t)(_Float16)0.0f;
      }
    }
#pragma unroll
    for (int i = 0; i < 2; ++i)
#pragma unroll
      for (int j = 0; j < 4; ++j)
        acc[i][j] = __builtin_amdgcn_mfma_f32_16x16x32_f16(af[i], bf[j], acc[i][j], 0, 0, 0);
  }
#pragma unroll
  for (int i = 0; i < 2; ++i)
#pragma unroll
    for (int j = 0; j < 4; ++j)
#pragma unroll
      for (int r = 0; r < 4; ++r) {
        const int k = m0 + i * 16 + fg * 4 + r;
        const int n = n0 + j * 16 + fr;
        const int kt32 = k >> 5, fgb = (k >> 3) & 3, e = k & 7;
        const int jg = n >> 4, frb = n & 15;
        Bf[(((size_t)kt32 * 8 + jg) * 64 + fgb * 16 + frb) * 8 + e] =
            (_Float16)acc[i][j][r];
      }
}

// ---------------------------------------------------------------------------
// GEMM partials: block (bx, ks) owns 64 batch rows x 128 cols x K-slice
// ks*1024..+1024 (16 iters of BK=64). 256 thr / 4 waves, wave tile 32x64.
// LDS single-buffer 32KB: Af[4096] f32 (src-XOR u^(r&7)), Bl[8192] f16
// (linear Bf 16KB chunk). m97 2-barrier loop: compute; sync; STAGE; sync.
// grid (256,4) = 1024 blocks = 4 blocks/CU co-resident.
__global__ __launch_bounds__(256, 4) void gemm_part_k(const float* __restrict__ A,
                                                      const _Float16* __restrict__ Bf,
                                                      float* __restrict__ part) {
  __shared__ __align__(16) char smem[32768];
  float*    Afs = (float*)smem;                 // [4096] f32  16KB
  _Float16* Bls = (_Float16*)(smem + 16384);    // [8192] f16  16KB

  const int t = threadIdx.x, lane = t & 63, w = t >> 6;
  const int fr = lane & 15, fg = lane >> 4;
  const int ks = blockIdx.y;
  const size_t row0 = (size_t)blockIdx.x * 64;
  const int k0 = ks * 1024;

  // staging: 32 instrs, id = w*8+q. id<16: A rows id*4+(lane>>4), 256B/row,
  // source-XOR-swizzled units; id>=16: B linear 1KB chunks of Bf tile.
#define STAGE(T)                                                              \
  do {                                                                        \
    _Pragma("unroll") for (int q_ = 0; q_ < 8; ++q_) {                        \
      const int id_ = w * 8 + q_;                                             \
      if (id_ < 16) {                                                         \
        const int r_ = id_ * 4 + (lane >> 4);                                 \
        gl_lds16f(A + (size_t)(row0 + r_) * D_IN + k0 + (T)*64 +              \
                      (((lane & 15) ^ (r_ & 7)) << 2),                        \
                  Afs + id_ * 256);                                           \
      } else {                                                                \
        const int ib_ = id_ - 16;                                             \
        gl_lds16h(Bf + ((size_t)(ks * 16 + (T))) * 8192 + ib_ * 512 + lane * 8, \
                  Bls + ib_ * 512);                                           \
      }                                                                       \
    }                                                                         \
  } while (0)

  // frag read offsets: wave tile rows wm*32..+32 (wm=w>>1), cols wn*64..+64
  const int wm = w >> 1, wn = w & 1;
  int aoff[2][2][2];  // [i][c][h]: row R=wm*32+i*16+fr, unit (c*8+fg*2+h)^(R&7)
#pragma unroll
  for (int i = 0; i < 2; ++i)
#pragma unroll
    for (int c = 0; c < 2; ++c)
#pragma unroll
      for (int h = 0; h < 2; ++h) {
        const int R = wm * 32 + i * 16 + fr;
        aoff[i][c][h] = R * 64 + (((c * 8 + fg * 2 + h) ^ (R & 7)) << 2);
      }
  int boff[2][4];
#pragma unroll
  for (int c = 0; c < 2; ++c)
#pragma unroll
    for (int j = 0; j < 4; ++j)
      boff[c][j] = c * 4096 + (wn * 4 + j) * 512 + lane * 8;

  f32x4_t acc[2][4] = {};

  STAGE(0);
  __syncthreads();
  for (int kt = 0; kt < 16; ++kt) {
#pragma unroll
    for (int c = 0; c < 2; ++c) {
      half8_t bfv[4];
#pragma unroll
      for (int j = 0; j < 4; ++j) bfv[j] = *(const half8_t*)(Bls + boff[c][j]);
#pragma unroll
      for (int i = 0; i < 2; ++i) {
        const float4 x0 = *(const float4*)(Afs + aoff[i][c][0]);
        const float4 x1 = *(const float4*)(Afs + aoff[i][c][1]);
        const half8_t af = cvt8(x0, x1);
#pragma unroll
        for (int j = 0; j < 4; ++j)
          acc[i][j] = __builtin_amdgcn_mfma_f32_16x16x32_f16(af, bfv[j], acc[i][j], 0, 0, 0);
      }
    }
    if (kt < 15) {
      __syncthreads();   // all waves done reading LDS
      STAGE(kt + 1);
      __syncthreads();   // compiler drains vmcnt(0) before barrier -> ready
    }
  }
#undef STAGE

  // epilogue: C/D layout row=fg*4+r, col=j*16+fr  [m89]
  float* pb = part + ((size_t)ks * NUM_B + row0) * 128;
#pragma unroll
  for (int i = 0; i < 2; ++i)
#pragma unroll
    for (int j = 0; j < 4; ++j) {
      const int col = wn * 64 + j * 16 + fr;
#pragma unroll
      for (int r = 0; r < 4; ++r)
        pb[(size_t)(wm * 32 + i * 16 + fg * 4 + r) * 128 + col] = acc[i][j][r];
    }
}

// ---------------------------------------------------------------------------
// Coalesced split-K reduce + gather + bias + log_softmax. One wave per row.
// Lane l holds cols {2l,2l+1}; gather via shuffle from lane aidx>>1.
__global__ __launch_bounds__(256) void softmax_k(const float* __restrict__ part,
                                                 const float* __restrict__ bqk,
                                                 const int* __restrict__ va,
                                                 const int* __restrict__ phase,
                                                 const int* __restrict__ trick,
                                                 const float* __restrict__ psig,
                                                 float* __restrict__ out) {
  const int t = threadIdx.x;
  const int lane = t & 63, w = t >> 6;
  const int b = blockIdx.x * 4 + w;

  float sx = 0.f, sy = 0.f;
#pragma unroll
  for (int ks = 0; ks < 4; ++ks) {
    const float2 v = *(const float2*)&part[((size_t)ks * NUM_B + b) * 128 + lane * 2];
    sx += v.x; sy += v.y;
  }

  int rank = -1, suit = 0;
  if (lane < N_ACT) {
    rank = va[((size_t)b * N_ACT + lane) * 2];
    suit = va[((size_t)b * N_ACT + lane) * 2 + 1];
  }
  const int ph = phase[b];
  const bool valid = (rank >= 0);
  const int aidx = valid ? (suit == 4 ? 80 : ph * 40 + suit * 9 + rank) : -1;
  const int nvalid = __popcll(__ballot(valid));

  const int srcl = valid ? (aidx >> 1) : 0;
  const float v0 = __shfl(sx, srcl);
  const float v1 = __shfl(sy, srcl);

  float attn_l = -INFINITY;
  if (valid) attn_l = (((aidx & 1) ? v1 : v0) + bqk[aidx]) * 0.0625f;  // /sqrt(256)

  if (ph == 1 && lane == 0) {
    const float ps = psig[trick[b]];
    const float nv = (float)nvalid;
    const float wv = (nv == 1.0f) ? 0.0f
                                  : logf(fmaxf((1.0f - ps) / ps * (nv - 1.0f), 1e-5f));
    attn_l += wv;
  }

  float m = attn_l;
#pragma unroll
  for (int off = 1; off < 64; off <<= 1) m = fmaxf(m, __shfl_xor(m, off));
  const float e = expf(attn_l - m);
  float ssum = e;
#pragma unroll
  for (int off = 1; off < 64; off <<= 1) ssum += __shfl_xor(ssum, off);
  const float o = attn_l - m - logf(ssum);
  // finite sentinel at masked positions (ref has -inf; (-inf)-(-inf)=NaN fails)
  if (lane < N_ACT) out[(size_t)b * N_ACT + lane] = valid ? o : -3.0e38f;
}

// ---------------------------------------------------------------------------
extern "C" void kernel_launch(void* const* d_in, const int* in_sizes, int n_in,
                              void* d_out, int out_size, void* d_ws, size_t ws_size,
                              hipStream_t stream) {
  const float* backbone = (const float*)d_in[0];
  const int*   va       = (const int*)d_in[1];
  const int*   phase    = (const int*)d_in[2];
  const int*   trick    = (const int*)d_in[3];
  const float* Wq       = (const float*)d_in[4];
  const float* bq       = (const float*)d_in[5];
  const float* keytab   = (const float*)d_in[6];
  const float* gamma    = (const float*)d_in[7];
  const float* beta     = (const float*)d_in[8];
  const float* psig     = (const float*)d_in[9];
  float* out = (float*)d_out;

  char* ws = (char*)d_ws;
  _Float16* Bf   = (_Float16*)ws;                             // 1 MB
  float* tableLN = (float*)(ws + (1u << 20));                 // 83 KB
  float* bqk     = (float*)(ws + (1u << 20) + (128u << 10));  // 324 B
  float* part    = (float*)(ws + (2u << 20));                 // 33.5 MB

  ln_table_k<<<dim3(81), 256, 0, stream>>>(keytab, gamma, beta, bq, tableLN, bqk);
  wk_gemm_k<<<dim3(64), 256, 0, stream>>>(Wq, tableLN, Bf);
  gemm_part_k<<<dim3(NUM_B / 64, 4), 256, 0, stream>>>(backbone, Bf, part);
  softmax_k<<<dim3(NUM_B / 4), 256, 0, stream>>>(part, bqk, va, phase, trick,
                                                 psig, out);
}